// Round 20
// baseline (227.666 us; speedup 1.0000x reference)
//
#include <hip/hip_runtime.h>
#include <stdint.h>

#define S_LEN 2048
#define DIMM  2048
#define NH    16
#define NKV   2

typedef __attribute__((ext_vector_type(8)))  short s16x8;
typedef __attribute__((ext_vector_type(8)))  unsigned short u16x8;
typedef __attribute__((ext_vector_type(4)))  float f32x4;
typedef __attribute__((ext_vector_type(16))) float f32x16;
typedef __attribute__((ext_vector_type(4)))  unsigned int u32x4;

__device__ __forceinline__ unsigned short f2bf(float f){
  unsigned int u = __builtin_bit_cast(unsigned int, f);
  u += 0x7fffu + ((u >> 16) & 1u);
  return (unsigned short)(u >> 16);
}

__device__ __forceinline__ float bf2f(unsigned short u){
  return __builtin_bit_cast(float, ((unsigned int)u) << 16);
}

__device__ __forceinline__ unsigned int cvtpk(float lo, float hi){
  unsigned int r;
  asm("v_cvt_pk_bf16_f32 %0, %1, %2" : "=v"(r) : "v"(lo), "v"(hi));
  return r;
}

__device__ __forceinline__ void gload16(const void* g, void* l){
  __builtin_amdgcn_global_load_lds(
      (const __attribute__((address_space(1))) unsigned int*)g,
      (__attribute__((address_space(3))) unsigned int*)l, 16, 0, 0);
}

// ---------------- fused fp32 -> bf16 convert for all 5 tensors ----------------
__global__ __launch_bounds__(256) void cvt_all(const float* __restrict__ x,
    const float* __restrict__ wq, const float* __restrict__ wk,
    const float* __restrict__ wv, const float* __restrict__ wo,
    unsigned short* __restrict__ xb, unsigned short* __restrict__ wqkvb,
    unsigned short* __restrict__ wob){
  long gid = (long)blockIdx.x * 256 + threadIdx.x;
  const float* src; unsigned short* dst; long off;
  if (gid < 1048576)      { src = x;  dst = xb;              off = gid; }
  else if (gid < 1572864) { src = wq; dst = wqkvb;           off = gid - 1048576; }
  else if (gid < 1638400) { src = wk; dst = wqkvb + 4194304; off = gid - 1572864; }
  else if (gid < 1703936) { src = wv; dst = wqkvb + 4718592; off = gid - 1638400; }
  else                    { src = wo; dst = wob;             off = gid - 1703936; }
  long i = off * 8;
  const float4* s4 = (const float4*)(src + i);
  float4 a = s4[0], b = s4[1];
  u16x8 o;
  o[0]=f2bf(a.x); o[1]=f2bf(a.y); o[2]=f2bf(a.z); o[3]=f2bf(a.w);
  o[4]=f2bf(b.x); o[5]=f2bf(b.y); o[6]=f2bf(b.z); o[7]=f2bf(b.w);
  *(u16x8*)(dst + i) = o;
}

// ---------------- C = A(bf16,[M,K]) @ W(bf16,[N,K])^T, out fp32 or bf16 ----------------
template<bool OBF16>
__global__ __launch_bounds__(256) void gemm_bt(const unsigned short* __restrict__ A,
                                               const unsigned short* __restrict__ W,
                                               void* __restrict__ Cv,
                                               int M, int N, int K){
  __shared__ __attribute__((aligned(16))) unsigned short As[128*64];
  __shared__ __attribute__((aligned(16))) unsigned short Bs[128*64];
  const int t = threadIdx.x;
  const int lane = t & 63, wave = t >> 6;
  const int l15 = lane & 15, g = lane >> 4;
  const int lid = blockIdx.y * gridDim.x + blockIdx.x;
  const int cpx = (gridDim.x * gridDim.y) >> 3;
  const int swz = (lid & 7) * cpx + (lid >> 3);
  const int m0 = (swz / gridDim.x) * 128, n0 = (swz % gridDim.x) * 128;
  const int wm = (wave >> 1) * 64, wn = (wave & 1) * 64;
  const int srow = t >> 3, sdblk = t & 7;
  const long ldsoff = (long)(t >> 6) * 1024;
  f32x4 acc[4][4] = {};
  for (int k0 = 0; k0 < K; k0 += 64){
    __syncthreads();
    #pragma unroll
    for (int r = 0; r < 4; ++r){
      int row = r*32 + srow;
      int db  = sdblk ^ (row & 7);
      gload16(A + (long)(m0+row)*K + k0 + db*8, (char*)As + r*4096 + ldsoff);
    }
    #pragma unroll
    for (int r = 0; r < 4; ++r){
      int row = r*32 + srow;
      int db  = sdblk ^ (row & 7);
      gload16(W + (long)(n0+row)*K + k0 + db*8, (char*)Bs + r*4096 + ldsoff);
    }
    __syncthreads();
    s16x8 af[4][2], bfr[4][2];
    #pragma unroll
    for (int mi = 0; mi < 4; ++mi)
      #pragma unroll
      for (int kc = 0; kc < 2; ++kc){
        int row = wm + mi*16 + l15;
        int db = (kc*4 + g) ^ (row & 7);
        af[mi][kc] = *(const s16x8*)(As + row*64 + db*8);
      }
    #pragma unroll
    for (int ni = 0; ni < 4; ++ni)
      #pragma unroll
      for (int kc = 0; kc < 2; ++kc){
        int row = wn + ni*16 + l15;
        int db = (kc*4 + g) ^ (row & 7);
        bfr[ni][kc] = *(const s16x8*)(Bs + row*64 + db*8);
      }
    #pragma unroll
    for (int mi = 0; mi < 4; ++mi)
      #pragma unroll
      for (int ni = 0; ni < 4; ++ni)
        #pragma unroll
        for (int kc = 0; kc < 2; ++kc)
          acc[mi][ni] = __builtin_amdgcn_mfma_f32_16x16x32_bf16(af[mi][kc], bfr[ni][kc], acc[mi][ni], 0, 0, 0);
  }
  #pragma unroll
  for (int mi = 0; mi < 4; ++mi)
    #pragma unroll
    for (int ni = 0; ni < 4; ++ni)
      #pragma unroll
      for (int rg = 0; rg < 4; ++rg){
        int row = m0 + wm + mi*16 + g*4 + rg;
        int col = n0 + wn + ni*16 + l15;
        if (OBF16)
          ((unsigned short*)Cv)[(long)row*N + col] = f2bf(acc[mi][ni][rg]);
        else
          ((float*)Cv)[(long)row*N + col] = acc[mi][ni][rg];
      }
}

// ---------------- fused: V transpose (bid<128) + RMSNorm/rotary (bid>=128) ----------------
__global__ __launch_bounds__(256) void postproc(const unsigned short* __restrict__ qkv,
    const float* __restrict__ cosb, const float* __restrict__ sinb,
    const float* __restrict__ qg, const float* __restrict__ kg,
    unsigned short* __restrict__ q_attn, unsigned short* __restrict__ k_attn,
    unsigned short* __restrict__ v_t){
  __shared__ __attribute__((aligned(16))) unsigned short lds[128*72];
  int bid = blockIdx.x;
  int t = threadIdx.x;
  if (bid < 128){
    int s0 = (bid & 31) * 64;
    int kv = (bid >> 5) & 1;
    int b  = bid >> 6;
    #pragma unroll
    for (int it = 0; it < 32; ++it){
      int idx = it*256 + t;
      int s = idx >> 7, d = idx & 127;
      lds[d*72 + s] = qkv[(long)(b*S_LEN + s0 + s)*2560 + 2304 + kv*128 + d];
    }
    __syncthreads();
    #pragma unroll
    for (int it = 0; it < 4; ++it){
      int c = it*256 + t;
      int d = c >> 3, s8 = c & 7;
      u16x8 vv = *(const u16x8*)(lds + d*72 + s8*8);
      *(u16x8*)(v_t + ((long)(b*NKV + kv)*128 + d)*S_LEN + s0 + s8*8) = vv;
    }
    return;
  }
  int wave = t >> 6, lane = t & 63;
  int rid = (bid - 128) * 4 + wave;
  int d0 = lane * 2;
  const unsigned short* src; unsigned short* dst; const float* gm; float sc; int s;
  if (rid < 2*S_LEN*NH){
    int bs = rid >> 4, h = rid & 15;
    int b = bs >> 11; s = bs & 2047;
    src = qkv + (long)bs*2560 + h*128;
    dst = q_attn + ((long)(b*NH + h)*S_LEN + s)*128;
    gm = qg; sc = 0.08838834764831845f * 1.4426950408889634f;  // scale * log2(e)
  } else {
    int r2 = rid - 2*S_LEN*NH;
    int bs = r2 >> 1, kv = r2 & 1;
    int b = bs >> 11; s = bs & 2047;
    src = qkv + (long)bs*2560 + 2048 + kv*128;
    dst = k_attn + ((long)(b*NKV + kv)*S_LEN + s)*128;
    gm = kg; sc = 1.0f;
  }
  unsigned int xw = *(const unsigned int*)(src + d0);
  float x0 = bf2f((unsigned short)(xw & 0xffff));
  float x1 = bf2f((unsigned short)(xw >> 16));
  float ss = x0*x0 + x1*x1;
  #pragma unroll
  for (int m = 1; m < 64; m <<= 1) ss += __shfl_xor(ss, m);
  float r = rsqrtf(ss * (1.0f/128.0f) + 1e-6f);
  float2 gv = *(const float2*)(gm + d0);
  float n0 = x0 * r * gv.x, n1 = x1 * r * gv.y;
  float p0 = __shfl_xor(n0, 32), p1 = __shfl_xor(n1, 32);
  float sgn = (d0 < 64) ? -1.f : 1.f;
  float2 c  = *(const float2*)(cosb + (long)s*128 + d0);
  float2 sn = *(const float2*)(sinb + (long)s*128 + d0);
  float o0 = (n0*c.x + sgn*p0*sn.x) * sc;
  float o1 = (n1*c.y + sgn*p1*sn.y) * sc;
  unsigned int pk = (unsigned int)f2bf(o0) | ((unsigned int)f2bf(o1) << 16);
  *(unsigned int*)(dst + d0) = pk;
}

// ---------------- flash attention: 32x32 MFMA, 2-wave blocks (QBLK=64), grid 1024 ----------------
// [r15/r19-verified base: 105 us] K double-buffered via global_load_lds (pre-swizzled
// source); V register-direct; swapped QK^T; cvt_pk+permlane32_swap P transpose.
// r20 change: row-max and row-sum as DEPTH-5 TREES (were 32-deep serial chains).
__global__ __launch_bounds__(128, 2) void attn_fwd(const unsigned short* __restrict__ q_attn,
    const unsigned short* __restrict__ k_attn, const unsigned short* __restrict__ v_t,
    unsigned short* __restrict__ attn_out, const int* __restrict__ pp){
  __shared__ __attribute__((aligned(16))) unsigned short Ks[2][64*128];
  const int p = pp[0];
  int bid = blockIdx.x;
  int qsb = 31 - (bid >> 5);         // LPT: longest chains dispatch first
  int bh = bid & 31;
  int h = bh & 15, b = bh >> 4;
  int kvh = h >> 3;
  int t = threadIdx.x, wave = t >> 6, lane = t & 63;
  int l31 = lane & 31, hi = lane >> 5;
  int QS = qsb * 64;
  int qw0 = QS + wave*32;            // this wave's 32 q-rows
  const int q = qw0 + l31;           // this lane's q-row (pair with lane^32)
  const unsigned short* qb = q_attn + ((long)(b*NH + h)*S_LEN + q)*128 + hi*8;
  s16x8 qf[8];
  #pragma unroll
  for (int m = 0; m < 8; ++m) qf[m] = *(const s16x8*)(qb + m*16);
  f32x16 O[4] = {};
  float mr = -3e38f, lr = 0.f;
  int kvend_w = (qw0 + 31 < p) ? ((p > qw0 + 32) ? p : qw0 + 32) : (qw0 + 32);
  int n_w = (kvend_w + 63) >> 6;
  int kvend_b = (QS + 63 < p) ? ((p > QS + 64) ? p : QS + 64) : (QS + 64);
  int n_blk = (kvend_b + 63) >> 6;
  const unsigned short* kb0 = k_attn + ((long)(b*NKV + kvh)*S_LEN)*128;
  const unsigned short* vb0 = v_t + ((long)(b*NKV + kvh)*128)*S_LEN;
  const int srow8 = t >> 4, sunit = t & 15;   // staging: 8 rows x 16 units per pass
  const long ldsoff = (long)wave * 1024;
  const unsigned short* vbase = vb0 + (long)l31*S_LEN + hi*8;

  // prologue: stage tile 0 into Ks[0] (pre-swizzled global src, linear LDS dest)
  #pragma unroll
  for (int r = 0; r < 8; ++r){
    int row = r*8 + srow8;
    int un  = sunit ^ (row & 15);
    gload16(kb0 + (long)row*128 + un*8, (char*)Ks[0] + r*2048 + ldsoff);
  }
  __syncthreads();
  int buf = 0;

  #pragma unroll 1
  for (int ti = 0; ti < n_blk; ++ti){
    int j0 = ti * 64;
    bool act = ti < n_w;             // warp-uniform
    s16x8 vfA[2][4], vfB[2][4];
    if (act){
      #pragma unroll
      for (int dt = 0; dt < 2; ++dt)
        #pragma unroll
        for (int km = 0; km < 4; ++km)
          vfA[dt][km] = *(const s16x8*)(vbase + (long)dt*32*S_LEN + j0 + km*16);
    }
    if (ti + 1 < n_blk){
      const unsigned short* kb = kb0 + (long)(j0 + 64)*128;
      char* dst = (char*)Ks[buf^1] + ldsoff;
      #pragma unroll
      for (int r = 0; r < 8; ++r){
        int row = r*8 + srow8;
        int un  = sunit ^ (row & 15);
        gload16(kb + (long)row*128 + un*8, dst + r*2048);
      }
    }
    if (act){
      // swapped QK^T: sa[kt] = mfma(K_frag, Q_frag) -> D[krow][q]
      const unsigned short* ksc = Ks[buf];
      f32x16 sa[2] = {};
      __builtin_amdgcn_s_setprio(1);
      #pragma unroll
      for (int kt = 0; kt < 2; ++kt){
        int row = kt*32 + l31;
        #pragma unroll
        for (int m = 0; m < 8; ++m){
          int un = (2*m + hi) ^ (row & 15);
          s16x8 kf = *(const s16x8*)(ksc + row*128 + un*8);
          sa[kt] = __builtin_amdgcn_mfma_f32_32x32x16_bf16(kf, qf[m], sa[kt], 0, 0, 0);
        }
      }
      __builtin_amdgcn_s_setprio(0);
      // V prefetch batch B (dt 2,3) — lands during softmax
      #pragma unroll
      for (int dt = 0; dt < 2; ++dt)
        #pragma unroll
        for (int km = 0; km < 4; ++km)
          vfB[dt][km] = *(const s16x8*)(vbase + (long)(dt+2)*32*S_LEN + j0 + km*16);
      // mask (if partial tile)
      bool full = (j0 + 63 <= qw0) || ((qw0 + 31 < p) && (j0 + 63 < p));
      if (!full){
        #pragma unroll
        for (int kt = 0; kt < 2; ++kt)
          #pragma unroll
          for (int rg = 0; rg < 16; ++rg){
            int j = j0 + kt*32 + (rg & 3) + 8*(rg >> 2) + 4*hi;
            bool ok = (j <= q) || ((q < p) && (j < p));
            sa[kt][rg] = ok ? sa[kt][rg] : -3e38f;
          }
      }
      // in-lane row max: depth-5 tree (was 32-deep serial chain)
      float mx[16];
      #pragma unroll
      for (int i = 0; i < 16; ++i) mx[i] = fmaxf(sa[0][i], sa[1][i]);
      #pragma unroll
      for (int off = 8; off >= 1; off >>= 1)
        #pragma unroll
        for (int i = 0; i < off; ++i) mx[i] = fmaxf(mx[i], mx[i+off]);
      float tm = fmaxf(mx[0], __shfl_xor(mx[0], 32));
      // online softmax (log2 domain; scale*log2e folded into Q)
      if (!__all(tm <= mr + 8.0f)){      // T13 defer-max
        float nm = fmaxf(mr, tm);
        float sfv = exp2f(mr - nm);
        mr = nm;
        lr *= sfv;
        float sfO[16];
        #pragma unroll
        for (int rg = 0; rg < 16; ++rg){
          int qr = (rg & 3) + 8*(rg >> 2) + 4*hi;
          sfO[rg] = __shfl(sfv, qr | (lane & 32));
        }
        #pragma unroll
        for (int dt = 0; dt < 4; ++dt)
          #pragma unroll
          for (int rg = 0; rg < 16; ++rg) O[dt][rg] *= sfO[rg];
      }
      // exp + row sum: 4 independent partial accumulators (was 32-deep serial chain)
      float rp0 = 0.f, rp1 = 0.f, rp2 = 0.f, rp3 = 0.f;
      #pragma unroll
      for (int kt = 0; kt < 2; ++kt)
        #pragma unroll
        for (int rg = 0; rg < 16; rg += 4){
          float e0 = exp2f(sa[kt][rg+0] - mr);
          float e1 = exp2f(sa[kt][rg+1] - mr);
          float e2 = exp2f(sa[kt][rg+2] - mr);
          float e3 = exp2f(sa[kt][rg+3] - mr);
          sa[kt][rg+0] = e0; sa[kt][rg+1] = e1;
          sa[kt][rg+2] = e2; sa[kt][rg+3] = e3;
          rp0 += e0; rp1 += e1; rp2 += e2; rp3 += e3;
        }
      float rs = (rp0 + rp1) + (rp2 + rp3);
      rs += __shfl_xor(rs, 32);
      lr += rs;
      // P -> PV A-frags: per km, 4 cvt_pk + 2 permlane32_swap (in-register transpose)
      __builtin_amdgcn_s_setprio(1);
      #pragma unroll
      for (int km = 0; km < 4; ++km){
        int base = (km & 1) * 8;
        const f32x16& s = sa[km >> 1];
        unsigned int a0 = cvtpk(s[base+0], s[base+1]);
        unsigned int b0 = cvtpk(s[base+4], s[base+5]);
        asm("v_permlane32_swap_b32 %0, %1" : "+v"(a0), "+v"(b0));
        unsigned int a1 = cvtpk(s[base+2], s[base+3]);
        unsigned int b1 = cvtpk(s[base+6], s[base+7]);
        asm("v_permlane32_swap_b32 %0, %1" : "+v"(a1), "+v"(b1));
        u32x4 w; w[0] = a0; w[1] = a1; w[2] = b0; w[3] = b1;
        s16x8 pf = __builtin_bit_cast(s16x8, w);
        #pragma unroll
        for (int dt = 0; dt < 2; ++dt)
          O[dt] = __builtin_amdgcn_mfma_f32_32x32x16_bf16(pf, vfA[dt][km], O[dt], 0, 0, 0);
        #pragma unroll
        for (int dt = 2; dt < 4; ++dt)
          O[dt] = __builtin_amdgcn_mfma_f32_32x32x16_bf16(pf, vfB[dt-2][km], O[dt], 0, 0, 0);
      }
      __builtin_amdgcn_s_setprio(0);
    }
    __syncthreads();   // drains next-tile stage + frees Ks[buf]
    buf ^= 1;
  }
  // epilogue: redistribute 1/lr (q=l31 domain) to O rows, write bf16
  float inv = 1.0f / lr;
  float invO[16];
  #pragma unroll
  for (int rg = 0; rg < 16; ++rg){
    int qr = (rg & 3) + 8*(rg >> 2) + 4*hi;
    invO[rg] = __shfl(inv, qr | (lane & 32));
  }
  #pragma unroll
  for (int dt = 0; dt < 4; ++dt)
    #pragma unroll
    for (int rg = 0; rg < 16; ++rg){
      int row = qw0 + (rg & 3) + 8*(rg >> 2) + 4*hi;
      int col = h*128 + dt*32 + l31;
      attn_out[(long)(b*S_LEN + row)*DIMM + col] = f2bf(O[dt][rg]*invO[rg]);
    }
}

extern "C" void kernel_launch(void* const* d_in, const int* in_sizes, int n_in,
                              void* d_out, int out_size, void* d_ws, size_t ws_size,
                              hipStream_t stream){
  const float* x    = (const float*)d_in[0];
  const float* cosb = (const float*)d_in[1];
  const float* sinb = (const float*)d_in[2];
  const float* wq   = (const float*)d_in[3];
  const float* wk   = (const float*)d_in[4];
  const float* wv   = (const float*)d_in[5];
  const float* wo   = (const float*)d_in[6];
  const float* qg   = (const float*)d_in[7];
  const float* kg   = (const float*)d_in[8];
  const int*   pp   = (const int*)d_in[9];

  char* ws = (char*)d_ws;
  unsigned short* xb    = (unsigned short*)(ws);                 // 4096x2048 bf16
  unsigned short* wqkvb = (unsigned short*)(ws + 16777216);      // 2560x2048 bf16
  unsigned short* wob   = (unsigned short*)(ws + 27262976);      // 2048x2048 bf16
  unsigned short* qkvb  = (unsigned short*)(ws + 35651584);      // 4096x2560 bf16
  unsigned short* qat   = (unsigned short*)(ws + 77594624);      // [B,16,S,128]
  unsigned short* kat   = (unsigned short*)(ws + 94371840);      // [B,2,S,128]
  unsigned short* vt    = (unsigned short*)(ws + 96468992);      // [B,2,128,S]
  unsigned short* aout  = (unsigned short*)(ws + 98566144);      // [B,S,2048]

  cvt_all<<<8704, 256, 0, stream>>>(x, wq, wk, wv, wo, xb, wqkvb, wob);

  gemm_bt<true><<<dim3(2560/128, 4096/128), 256, 0, stream>>>(xb, wqkvb, qkvb, 4096, 2560, 2048);
  postproc<<<18560, 256, 0, stream>>>(qkvb, cosb, sinb, qg, kg, qat, kat, vt);
  attn_fwd<<<1024, 128, 0, stream>>>(qat, kat, vt, aout, pp);
  gemm_bt<false><<<dim3(2048/128, 4096/128), 256, 0, stream>>>(aout, wob, (float*)d_out, 4096, 2048, 2048);
}

// Round 21
// 226.436 us; speedup vs baseline: 1.0054x; 1.0054x over previous
//
#include <hip/hip_runtime.h>
#include <stdint.h>

#define S_LEN 2048
#define DIMM  2048
#define NH    16
#define NKV   2

typedef __attribute__((ext_vector_type(8)))  short s16x8;
typedef __attribute__((ext_vector_type(8)))  unsigned short u16x8;
typedef __attribute__((ext_vector_type(4)))  float f32x4;
typedef __attribute__((ext_vector_type(16))) float f32x16;
typedef __attribute__((ext_vector_type(4)))  unsigned int u32x4;

__device__ __forceinline__ unsigned short f2bf(float f){
  unsigned int u = __builtin_bit_cast(unsigned int, f);
  u += 0x7fffu + ((u >> 16) & 1u);
  return (unsigned short)(u >> 16);
}

__device__ __forceinline__ float bf2f(unsigned short u){
  return __builtin_bit_cast(float, ((unsigned int)u) << 16);
}

__device__ __forceinline__ unsigned int cvtpk(float lo, float hi){
  unsigned int r;
  asm("v_cvt_pk_bf16_f32 %0, %1, %2" : "=v"(r) : "v"(lo), "v"(hi));
  return r;
}

__device__ __forceinline__ void gload16(const void* g, void* l){
  __builtin_amdgcn_global_load_lds(
      (const __attribute__((address_space(1))) unsigned int*)g,
      (__attribute__((address_space(3))) unsigned int*)l, 16, 0, 0);
}

// ---------------- fused fp32 -> bf16 convert for all 5 tensors ----------------
__global__ __launch_bounds__(256) void cvt_all(const float* __restrict__ x,
    const float* __restrict__ wq, const float* __restrict__ wk,
    const float* __restrict__ wv, const float* __restrict__ wo,
    unsigned short* __restrict__ xb, unsigned short* __restrict__ wqkvb,
    unsigned short* __restrict__ wob){
  long gid = (long)blockIdx.x * 256 + threadIdx.x;
  const float* src; unsigned short* dst; long off;
  if (gid < 1048576)      { src = x;  dst = xb;              off = gid; }
  else if (gid < 1572864) { src = wq; dst = wqkvb;           off = gid - 1048576; }
  else if (gid < 1638400) { src = wk; dst = wqkvb + 4194304; off = gid - 1572864; }
  else if (gid < 1703936) { src = wv; dst = wqkvb + 4718592; off = gid - 1638400; }
  else                    { src = wo; dst = wob;             off = gid - 1703936; }
  long i = off * 8;
  const float4* s4 = (const float4*)(src + i);
  float4 a = s4[0], b = s4[1];
  u16x8 o;
  o[0]=f2bf(a.x); o[1]=f2bf(a.y); o[2]=f2bf(a.z); o[3]=f2bf(a.w);
  o[4]=f2bf(b.x); o[5]=f2bf(b.y); o[6]=f2bf(b.z); o[7]=f2bf(b.w);
  *(u16x8*)(dst + i) = o;
}

// ---------------- C = A(bf16,[M,K]) @ W(bf16,[N,K])^T, out fp32 or bf16 ----------------
template<bool OBF16>
__global__ __launch_bounds__(256) void gemm_bt(const unsigned short* __restrict__ A,
                                               const unsigned short* __restrict__ W,
                                               void* __restrict__ Cv,
                                               int M, int N, int K){
  __shared__ __attribute__((aligned(16))) unsigned short As[128*64];
  __shared__ __attribute__((aligned(16))) unsigned short Bs[128*64];
  const int t = threadIdx.x;
  const int lane = t & 63, wave = t >> 6;
  const int l15 = lane & 15, g = lane >> 4;
  const int lid = blockIdx.y * gridDim.x + blockIdx.x;
  const int cpx = (gridDim.x * gridDim.y) >> 3;
  const int swz = (lid & 7) * cpx + (lid >> 3);
  const int m0 = (swz / gridDim.x) * 128, n0 = (swz % gridDim.x) * 128;
  const int wm = (wave >> 1) * 64, wn = (wave & 1) * 64;
  const int srow = t >> 3, sdblk = t & 7;
  const long ldsoff = (long)(t >> 6) * 1024;
  f32x4 acc[4][4] = {};
  for (int k0 = 0; k0 < K; k0 += 64){
    __syncthreads();
    #pragma unroll
    for (int r = 0; r < 4; ++r){
      int row = r*32 + srow;
      int db  = sdblk ^ (row & 7);
      gload16(A + (long)(m0+row)*K + k0 + db*8, (char*)As + r*4096 + ldsoff);
    }
    #pragma unroll
    for (int r = 0; r < 4; ++r){
      int row = r*32 + srow;
      int db  = sdblk ^ (row & 7);
      gload16(W + (long)(n0+row)*K + k0 + db*8, (char*)Bs + r*4096 + ldsoff);
    }
    __syncthreads();
    s16x8 af[4][2], bfr[4][2];
    #pragma unroll
    for (int mi = 0; mi < 4; ++mi)
      #pragma unroll
      for (int kc = 0; kc < 2; ++kc){
        int row = wm + mi*16 + l15;
        int db = (kc*4 + g) ^ (row & 7);
        af[mi][kc] = *(const s16x8*)(As + row*64 + db*8);
      }
    #pragma unroll
    for (int ni = 0; ni < 4; ++ni)
      #pragma unroll
      for (int kc = 0; kc < 2; ++kc){
        int row = wn + ni*16 + l15;
        int db = (kc*4 + g) ^ (row & 7);
        bfr[ni][kc] = *(const s16x8*)(Bs + row*64 + db*8);
      }
    #pragma unroll
    for (int mi = 0; mi < 4; ++mi)
      #pragma unroll
      for (int ni = 0; ni < 4; ++ni)
        #pragma unroll
        for (int kc = 0; kc < 2; ++kc)
          acc[mi][ni] = __builtin_amdgcn_mfma_f32_16x16x32_bf16(af[mi][kc], bfr[ni][kc], acc[mi][ni], 0, 0, 0);
  }
  #pragma unroll
  for (int mi = 0; mi < 4; ++mi)
    #pragma unroll
    for (int ni = 0; ni < 4; ++ni)
      #pragma unroll
      for (int rg = 0; rg < 4; ++rg){
        int row = m0 + wm + mi*16 + g*4 + rg;
        int col = n0 + wn + ni*16 + l15;
        if (OBF16)
          ((unsigned short*)Cv)[(long)row*N + col] = f2bf(acc[mi][ni][rg]);
        else
          ((float*)Cv)[(long)row*N + col] = acc[mi][ni][rg];
      }
}

// ---------------- fused: V transpose (bid<128) + RMSNorm/rotary (bid>=128) ----------------
__global__ __launch_bounds__(256) void postproc(const unsigned short* __restrict__ qkv,
    const float* __restrict__ cosb, const float* __restrict__ sinb,
    const float* __restrict__ qg, const float* __restrict__ kg,
    unsigned short* __restrict__ q_attn, unsigned short* __restrict__ k_attn,
    unsigned short* __restrict__ v_t){
  __shared__ __attribute__((aligned(16))) unsigned short lds[128*72];
  int bid = blockIdx.x;
  int t = threadIdx.x;
  if (bid < 128){
    int s0 = (bid & 31) * 64;
    int kv = (bid >> 5) & 1;
    int b  = bid >> 6;
    #pragma unroll
    for (int it = 0; it < 32; ++it){
      int idx = it*256 + t;
      int s = idx >> 7, d = idx & 127;
      lds[d*72 + s] = qkv[(long)(b*S_LEN + s0 + s)*2560 + 2304 + kv*128 + d];
    }
    __syncthreads();
    #pragma unroll
    for (int it = 0; it < 4; ++it){
      int c = it*256 + t;
      int d = c >> 3, s8 = c & 7;
      u16x8 vv = *(const u16x8*)(lds + d*72 + s8*8);
      *(u16x8*)(v_t + ((long)(b*NKV + kv)*128 + d)*S_LEN + s0 + s8*8) = vv;
    }
    return;
  }
  int wave = t >> 6, lane = t & 63;
  int rid = (bid - 128) * 4 + wave;
  int d0 = lane * 2;
  const unsigned short* src; unsigned short* dst; const float* gm; float sc; int s;
  if (rid < 2*S_LEN*NH){
    int bs = rid >> 4, h = rid & 15;
    int b = bs >> 11; s = bs & 2047;
    src = qkv + (long)bs*2560 + h*128;
    dst = q_attn + ((long)(b*NH + h)*S_LEN + s)*128;
    gm = qg; sc = 0.08838834764831845f * 1.4426950408889634f;  // scale * log2(e)
  } else {
    int r2 = rid - 2*S_LEN*NH;
    int bs = r2 >> 1, kv = r2 & 1;
    int b = bs >> 11; s = bs & 2047;
    src = qkv + (long)bs*2560 + 2048 + kv*128;
    dst = k_attn + ((long)(b*NKV + kv)*S_LEN + s)*128;
    gm = kg; sc = 1.0f;
  }
  unsigned int xw = *(const unsigned int*)(src + d0);
  float x0 = bf2f((unsigned short)(xw & 0xffff));
  float x1 = bf2f((unsigned short)(xw >> 16));
  float ss = x0*x0 + x1*x1;
  #pragma unroll
  for (int m = 1; m < 64; m <<= 1) ss += __shfl_xor(ss, m);
  float r = rsqrtf(ss * (1.0f/128.0f) + 1e-6f);
  float2 gv = *(const float2*)(gm + d0);
  float n0 = x0 * r * gv.x, n1 = x1 * r * gv.y;
  float p0 = __shfl_xor(n0, 32), p1 = __shfl_xor(n1, 32);
  float sgn = (d0 < 64) ? -1.f : 1.f;
  float2 c  = *(const float2*)(cosb + (long)s*128 + d0);
  float2 sn = *(const float2*)(sinb + (long)s*128 + d0);
  float o0 = (n0*c.x + sgn*p0*sn.x) * sc;
  float o1 = (n1*c.y + sgn*p1*sn.y) * sc;
  unsigned int pk = (unsigned int)f2bf(o0) | ((unsigned int)f2bf(o1) << 16);
  *(unsigned int*)(dst + d0) = pk;
}

// ---------------- flash attention: 32x32 MFMA, 2-wave blocks (QBLK=64), grid 1024 ----------------
// [r15/r19-verified: 105 us] K double-buffered via global_load_lds (pre-swizzled source);
// V register-direct; swapped QK^T; in-lane softmax; cvt_pk+permlane32_swap P transpose.
__global__ __launch_bounds__(128, 2) void attn_fwd(const unsigned short* __restrict__ q_attn,
    const unsigned short* __restrict__ k_attn, const unsigned short* __restrict__ v_t,
    unsigned short* __restrict__ attn_out, const int* __restrict__ pp){
  __shared__ __attribute__((aligned(16))) unsigned short Ks[2][64*128];
  const int p = pp[0];
  int bid = blockIdx.x;
  int qsb = 31 - (bid >> 5);         // LPT: longest chains dispatch first
  int bh = bid & 31;
  int h = bh & 15, b = bh >> 4;
  int kvh = h >> 3;
  int t = threadIdx.x, wave = t >> 6, lane = t & 63;
  int l31 = lane & 31, hi = lane >> 5;
  int QS = qsb * 64;
  int qw0 = QS + wave*32;            // this wave's 32 q-rows
  const int q = qw0 + l31;           // this lane's q-row (pair with lane^32)
  const unsigned short* qb = q_attn + ((long)(b*NH + h)*S_LEN + q)*128 + hi*8;
  s16x8 qf[8];
  #pragma unroll
  for (int m = 0; m < 8; ++m) qf[m] = *(const s16x8*)(qb + m*16);
  f32x16 O[4] = {};
  float mr = -3e38f, lr = 0.f;
  int kvend_w = (qw0 + 31 < p) ? ((p > qw0 + 32) ? p : qw0 + 32) : (qw0 + 32);
  int n_w = (kvend_w + 63) >> 6;
  int kvend_b = (QS + 63 < p) ? ((p > QS + 64) ? p : QS + 64) : (QS + 64);
  int n_blk = (kvend_b + 63) >> 6;
  const unsigned short* kb0 = k_attn + ((long)(b*NKV + kvh)*S_LEN)*128;
  const unsigned short* vb0 = v_t + ((long)(b*NKV + kvh)*128)*S_LEN;
  const int srow8 = t >> 4, sunit = t & 15;   // staging: 8 rows x 16 units per pass
  const long ldsoff = (long)wave * 1024;
  const unsigned short* vbase = vb0 + (long)l31*S_LEN + hi*8;

  // prologue: stage tile 0 into Ks[0] (pre-swizzled global src, linear LDS dest)
  #pragma unroll
  for (int r = 0; r < 8; ++r){
    int row = r*8 + srow8;
    int un  = sunit ^ (row & 15);
    gload16(kb0 + (long)row*128 + un*8, (char*)Ks[0] + r*2048 + ldsoff);
  }
  __syncthreads();
  int buf = 0;

  #pragma unroll 1
  for (int ti = 0; ti < n_blk; ++ti){
    int j0 = ti * 64;
    bool act = ti < n_w;             // warp-uniform
    s16x8 vfA[2][4], vfB[2][4];
    if (act){
      #pragma unroll
      for (int dt = 0; dt < 2; ++dt)
        #pragma unroll
        for (int km = 0; km < 4; ++km)
          vfA[dt][km] = *(const s16x8*)(vbase + (long)dt*32*S_LEN + j0 + km*16);
    }
    if (ti + 1 < n_blk){
      const unsigned short* kb = kb0 + (long)(j0 + 64)*128;
      char* dst = (char*)Ks[buf^1] + ldsoff;
      #pragma unroll
      for (int r = 0; r < 8; ++r){
        int row = r*8 + srow8;
        int un  = sunit ^ (row & 15);
        gload16(kb + (long)row*128 + un*8, dst + r*2048);
      }
    }
    if (act){
      // swapped QK^T: sa[kt] = mfma(K_frag, Q_frag) -> D[krow][q]
      const unsigned short* ksc = Ks[buf];
      f32x16 sa[2] = {};
      __builtin_amdgcn_s_setprio(1);
      #pragma unroll
      for (int kt = 0; kt < 2; ++kt){
        int row = kt*32 + l31;
        #pragma unroll
        for (int m = 0; m < 8; ++m){
          int un = (2*m + hi) ^ (row & 15);
          s16x8 kf = *(const s16x8*)(ksc + row*128 + un*8);
          sa[kt] = __builtin_amdgcn_mfma_f32_32x32x16_bf16(kf, qf[m], sa[kt], 0, 0, 0);
        }
      }
      __builtin_amdgcn_s_setprio(0);
      // V prefetch batch B (dt 2,3) — lands during softmax
      #pragma unroll
      for (int dt = 0; dt < 2; ++dt)
        #pragma unroll
        for (int km = 0; km < 4; ++km)
          vfB[dt][km] = *(const s16x8*)(vbase + (long)(dt+2)*32*S_LEN + j0 + km*16);
      // mask + in-lane row max (32 scores of q in this lane; rest in lane^32)
      float tm = -3e38f;
      bool full = (j0 + 63 <= qw0) || ((qw0 + 31 < p) && (j0 + 63 < p));
      if (full){
        #pragma unroll
        for (int kt = 0; kt < 2; ++kt)
          #pragma unroll
          for (int rg = 0; rg < 16; ++rg) tm = fmaxf(tm, sa[kt][rg]);
      } else {
        #pragma unroll
        for (int kt = 0; kt < 2; ++kt)
          #pragma unroll
          for (int rg = 0; rg < 16; ++rg){
            int j = j0 + kt*32 + (rg & 3) + 8*(rg >> 2) + 4*hi;
            bool ok = (j <= q) || ((q < p) && (j < p));
            float sv = ok ? sa[kt][rg] : -3e38f;
            sa[kt][rg] = sv;
            tm = fmaxf(tm, sv);
          }
      }
      tm = fmaxf(tm, __shfl_xor(tm, 32));
      // online softmax (log2 domain; scale*log2e folded into Q)
      if (!__all(tm <= mr + 8.0f)){      // T13 defer-max
        float nm = fmaxf(mr, tm);
        float sfv = exp2f(mr - nm);
        mr = nm;
        lr *= sfv;
        float sfO[16];
        #pragma unroll
        for (int rg = 0; rg < 16; ++rg){
          int qr = (rg & 3) + 8*(rg >> 2) + 4*hi;
          sfO[rg] = __shfl(sfv, qr | (lane & 32));
        }
        #pragma unroll
        for (int dt = 0; dt < 4; ++dt)
          #pragma unroll
          for (int rg = 0; rg < 16; ++rg) O[dt][rg] *= sfO[rg];
      }
      float rs = 0.f;
      #pragma unroll
      for (int kt = 0; kt < 2; ++kt)
        #pragma unroll
        for (int rg = 0; rg < 16; ++rg){
          float e = exp2f(sa[kt][rg] - mr);
          sa[kt][rg] = e;
          rs += e;
        }
      rs += __shfl_xor(rs, 32);
      lr += rs;
      // P -> PV A-frags: per km, 4 cvt_pk + 2 permlane32_swap (in-register transpose)
      __builtin_amdgcn_s_setprio(1);
      #pragma unroll
      for (int km = 0; km < 4; ++km){
        int base = (km & 1) * 8;
        const f32x16& s = sa[km >> 1];
        unsigned int a0 = cvtpk(s[base+0], s[base+1]);
        unsigned int b0 = cvtpk(s[base+4], s[base+5]);
        asm("v_permlane32_swap_b32 %0, %1" : "+v"(a0), "+v"(b0));
        unsigned int a1 = cvtpk(s[base+2], s[base+3]);
        unsigned int b1 = cvtpk(s[base+6], s[base+7]);
        asm("v_permlane32_swap_b32 %0, %1" : "+v"(a1), "+v"(b1));
        u32x4 w; w[0] = a0; w[1] = a1; w[2] = b0; w[3] = b1;
        s16x8 pf = __builtin_bit_cast(s16x8, w);
        #pragma unroll
        for (int dt = 0; dt < 2; ++dt)
          O[dt] = __builtin_amdgcn_mfma_f32_32x32x16_bf16(pf, vfA[dt][km], O[dt], 0, 0, 0);
        #pragma unroll
        for (int dt = 2; dt < 4; ++dt)
          O[dt] = __builtin_amdgcn_mfma_f32_32x32x16_bf16(pf, vfB[dt-2][km], O[dt], 0, 0, 0);
      }
      __builtin_amdgcn_s_setprio(0);
    }
    __syncthreads();   // drains next-tile stage + frees Ks[buf]
    buf ^= 1;
  }
  // epilogue: redistribute 1/lr (q=l31 domain) to O rows, write bf16
  float inv = 1.0f / lr;
  float invO[16];
  #pragma unroll
  for (int rg = 0; rg < 16; ++rg){
    int qr = (rg & 3) + 8*(rg >> 2) + 4*hi;
    invO[rg] = __shfl(inv, qr | (lane & 32));
  }
  #pragma unroll
  for (int dt = 0; dt < 4; ++dt)
    #pragma unroll
    for (int rg = 0; rg < 16; ++rg){
      int row = qw0 + (rg & 3) + 8*(rg >> 2) + 4*hi;
      int col = h*128 + dt*32 + l31;
      attn_out[(long)(b*S_LEN + row)*DIMM + col] = f2bf(O[dt][rg]*invO[rg]);
    }
}

extern "C" void kernel_launch(void* const* d_in, const int* in_sizes, int n_in,
                              void* d_out, int out_size, void* d_ws, size_t ws_size,
                              hipStream_t stream){
  const float* x    = (const float*)d_in[0];
  const float* cosb = (const float*)d_in[1];
  const float* sinb = (const float*)d_in[2];
  const float* wq   = (const float*)d_in[3];
  const float* wk   = (const float*)d_in[4];
  const float* wv   = (const float*)d_in[5];
  const float* wo   = (const float*)d_in[6];
  const float* qg   = (const float*)d_in[7];
  const float* kg   = (const float*)d_in[8];
  const int*   pp   = (const int*)d_in[9];

  char* ws = (char*)d_ws;
  unsigned short* xb    = (unsigned short*)(ws);                 // 4096x2048 bf16
  unsigned short* wqkvb = (unsigned short*)(ws + 16777216);      // 2560x2048 bf16
  unsigned short* wob   = (unsigned short*)(ws + 27262976);      // 2048x2048 bf16
  unsigned short* qkvb  = (unsigned short*)(ws + 35651584);      // 4096x2560 bf16
  unsigned short* qat   = (unsigned short*)(ws + 77594624);      // [B,16,S,128]
  unsigned short* kat   = (unsigned short*)(ws + 94371840);      // [B,2,S,128]
  unsigned short* vt    = (unsigned short*)(ws + 96468992);      // [B,2,128,S]
  unsigned short* aout  = (unsigned short*)(ws + 98566144);      // [B,S,2048]

  cvt_all<<<8704, 256, 0, stream>>>(x, wq, wk, wv, wo, xb, wqkvb, wob);

  gemm_bt<true><<<dim3(2560/128, 4096/128), 256, 0, stream>>>(xb, wqkvb, qkvb, 4096, 2560, 2048);
  postproc<<<18560, 256, 0, stream>>>(qkvb, cosb, sinb, qg, kg, qat, kat, vt);
  attn_fwd<<<1024, 128, 0, stream>>>(qat, kat, vt, aout, pp);
  gemm_bt<false><<<dim3(2048/128, 4096/128), 256, 0, stream>>>(aout, wob, (float*)d_out, 4096, 2048, 2048);
}